// Round 1
// baseline (2580.769 us; speedup 1.0000x reference)
//
#include <hip/hip_runtime.h>
#include <hip/hip_bf16.h>

#define TB 512
#define NB 64
#define HID 300
#define HHALF 150
#define G4 600
#define KP 320
#define MTOT (NB*TB)
#define NTAG 16
#define NEGV -10000.0f

using short8 = __attribute__((ext_vector_type(8))) short;
using f32x4  = __attribute__((ext_vector_type(4))) float;

__device__ __forceinline__ unsigned short f2bf(float f){
  union { float f; unsigned u; } v; v.f = f;
  unsigned r = v.u + 0x7FFFu + ((v.u >> 16) & 1u);
  return (unsigned short)(r >> 16);
}
__device__ __forceinline__ float fsig(float x){ return __fdividef(1.f, 1.f + __expf(-x)); }
__device__ __forceinline__ float ftanh(float x){ return 1.f - __fdividef(2.f, __expf(2.f*x) + 1.f); }

// ---- staging / conversion kernels ----
__global__ void k_gather_embed(const int* __restrict__ x, const float* __restrict__ emb,
                               unsigned short* __restrict__ Abf){
  long long total = (long long)MTOT * KP;
  for (long long idx = (long long)blockIdx.x*blockDim.x + threadIdx.x; idx < total;
       idx += (long long)gridDim.x*blockDim.x){
    int m = (int)(idx / KP), k = (int)(idx % KP);
    float v = 0.f;
    if (k < HID) v = emb[(long long)x[m]*HID + k];
    Abf[idx] = f2bf(v);
  }
}

__global__ void k_cvt_h(const float* __restrict__ h, unsigned short* __restrict__ Abf){
  long long total = (long long)MTOT * KP;
  for (long long idx = (long long)blockIdx.x*blockDim.x + threadIdx.x; idx < total;
       idx += (long long)gridDim.x*blockDim.x){
    int m = (int)(idx / KP), k = (int)(idx % KP);
    Abf[idx] = f2bf(k < HID ? h[(long long)m*HID + k] : 0.f);
  }
}

__global__ void k_cvt_w(const float* __restrict__ Wih, const float* __restrict__ bih,
                        const float* __restrict__ bhh,
                        unsigned short* __restrict__ Wbf, float* __restrict__ bsum){
  int idx = blockIdx.x*blockDim.x + threadIdx.x;
  if (idx >= 1216*KP) return;
  int n = idx / KP, k = idx % KP;
  float v = (n < 1200 && k < HID) ? Wih[(long long)n*HID + k] : 0.f;
  Wbf[idx] = f2bf(v);
  if (k == 0) bsum[n] = (n < 1200) ? (bih[n] + bhh[n]) : 0.f;
}

// ---- bf16 MFMA projection GEMM: pre[dir][m][j] = A(m,k) @ W(n,k)^T + bsum ----
// A: (32768 x 320) bf16 row-major, W: (1216 x 320) bf16 row-major, n = dir*600+j
__global__ __launch_bounds__(256) void k_proj(const unsigned short* __restrict__ A,
                                              const unsigned short* __restrict__ Wb,
                                              const float* __restrict__ bsum,
                                              float* __restrict__ pre){
  int m0 = blockIdx.x * 128;
  int n0 = blockIdx.y * 64;
  int wid = threadIdx.x >> 6, lane = threadIdx.x & 63;
  int la = lane & 15, lk = lane >> 4;
  int mw = m0 + wid*32;
  f32x4 acc[2][4];
  #pragma unroll
  for (int i=0;i<2;i++){
    #pragma unroll
    for (int j=0;j<4;j++){ acc[i][j][0]=0.f; acc[i][j][1]=0.f; acc[i][j][2]=0.f; acc[i][j][3]=0.f; }
  }
  const unsigned short* Ap = A  + (long long)(mw + la)*KP + lk*8;
  const unsigned short* Bp = Wb + (long long)(n0 + la)*KP + lk*8;
  #pragma unroll 2
  for (int kk=0; kk<KP; kk+=32){
    short8 a0 = *(const short8*)(Ap + kk);
    short8 a1 = *(const short8*)(Ap + 16*KP + kk);
    short8 b0 = *(const short8*)(Bp + kk);
    short8 b1 = *(const short8*)(Bp + 16*KP + kk);
    short8 b2 = *(const short8*)(Bp + 32*KP + kk);
    short8 b3 = *(const short8*)(Bp + 48*KP + kk);
    acc[0][0] = __builtin_amdgcn_mfma_f32_16x16x32_bf16(a0,b0,acc[0][0],0,0,0);
    acc[0][1] = __builtin_amdgcn_mfma_f32_16x16x32_bf16(a0,b1,acc[0][1],0,0,0);
    acc[0][2] = __builtin_amdgcn_mfma_f32_16x16x32_bf16(a0,b2,acc[0][2],0,0,0);
    acc[0][3] = __builtin_amdgcn_mfma_f32_16x16x32_bf16(a0,b3,acc[0][3],0,0,0);
    acc[1][0] = __builtin_amdgcn_mfma_f32_16x16x32_bf16(a1,b0,acc[1][0],0,0,0);
    acc[1][1] = __builtin_amdgcn_mfma_f32_16x16x32_bf16(a1,b1,acc[1][1],0,0,0);
    acc[1][2] = __builtin_amdgcn_mfma_f32_16x16x32_bf16(a1,b2,acc[1][2],0,0,0);
    acc[1][3] = __builtin_amdgcn_mfma_f32_16x16x32_bf16(a1,b3,acc[1][3],0,0,0);
  }
  #pragma unroll
  for (int ms=0; ms<2; ms++){
    #pragma unroll
    for (int ns=0; ns<4; ns++){
      int n = n0 + ns*16 + la;
      if (n < 1200){
        int dir = (n >= 600) ? 1 : 0;
        int j = n - dir*600;
        float bs = bsum[n];
        #pragma unroll
        for (int r=0;r<4;r++){
          int row = mw + ms*16 + lk*4 + r;
          pre[((long long)dir*MTOT + row)*G4 + j] = acc[ms][ns][r] + bs;
        }
      }
    }
  }
}

// ---- LSTM recurrence: one block per (dir, batch). Whh row in VGPRs. ----
__global__ __launch_bounds__(640) void k_rec(const float* __restrict__ pre,
                                             const float* __restrict__ Whh,
                                             const int* __restrict__ x,
                                             float* __restrict__ hout){
  int dir = blockIdx.x >> 6;
  int b   = blockIdx.x & 63;
  int tid = threadIdx.x;
  __shared__ __align__(16) float h_lds[152];
  __shared__ float g_lds[G4];
  float w[152];
  if (tid < G4){
    const float2* wp = (const float2*)(Whh + (long long)(dir*G4 + tid)*HHALF);
    #pragma unroll
    for (int q=0;q<75;q++){ float2 v = wp[q]; w[2*q] = v.x; w[2*q+1] = v.y; }
    w[150] = 0.f; w[151] = 0.f;
  }
  if (tid < 152) h_lds[tid] = 0.f;
  float c = 0.f;
  const float* preB = pre + ((long long)dir*MTOT + (long long)b*TB)*G4;
  const int* xb = x + b*TB;
  float* hb = hout + (long long)b*TB*HID + dir*HHALF;
  __syncthreads();
  #pragma unroll 1
  for (int s=0; s<TB; s++){
    int t = dir ? (TB-1-s) : s;
    int xv = xb[t];
    if (xv > 0){
      if (tid < G4){
        float pv = preB[(long long)t*G4 + tid];
        float a0 = 0.f, a1 = 0.f;
        #pragma unroll
        for (int q=0;q<38;q++){
          float4 hv = *(const float4*)(&h_lds[4*q]);
          a0 += hv.x * w[4*q+0];
          a1 += hv.y * w[4*q+1];
          a0 += hv.z * w[4*q+2];
          a1 += hv.w * w[4*q+3];
        }
        g_lds[tid] = pv + a0 + a1;
      }
      __syncthreads();
      if (tid < HHALF){
        float ig = g_lds[tid], fg = g_lds[HHALF+tid], gg = g_lds[2*HHALF+tid], og = g_lds[3*HHALF+tid];
        float cn = fsig(fg)*c + fsig(ig)*ftanh(gg);
        float hn = fsig(og)*ftanh(cn);
        h_lds[tid] = hn;
        c = cn;
        hb[(long long)t*HID + tid] = hn;
      }
      __syncthreads();
    } else {
      // masked step: state unchanged, output = carry
      if (tid < HHALF) hb[(long long)t*HID + tid] = h_lds[tid];
    }
  }
}

// ---- emissions: (h2 @ Wout.T + bout) * mask ----
__global__ __launch_bounds__(256) void k_emis(const float* __restrict__ h2,
                                              const float* __restrict__ Wout,
                                              const float* __restrict__ bout,
                                              const int* __restrict__ x,
                                              float* __restrict__ emis){
  int m = blockIdx.x*16 + (threadIdx.x >> 4);
  int n = threadIdx.x & 15;
  const float* hr = h2 + (long long)m*HID;
  const float* wr = Wout + n*HID;
  float acc = 0.f;
  #pragma unroll 4
  for (int k=0;k<HID;k++) acc += hr[k]*wr[k];
  float mm = (x[m] > 0) ? 1.f : 0.f;
  emis[(long long)m*NTAG + n] = (acc + bout[n]) * mm;
}

// ---- CRF partition: one block (1 wave) per batch ----
__global__ __launch_bounds__(64) void k_crf_part(const float* __restrict__ emis,
                                                 const float* __restrict__ trans,
                                                 const int* __restrict__ x,
                                                 float* __restrict__ out){
  int b = blockIdx.x;
  int lane = threadIdx.x;
  int i = lane & 15, q = lane >> 4;
  float t0 = trans[i*16 + q*4 + 0];
  float t1 = trans[i*16 + q*4 + 1];
  float t2 = trans[i*16 + q*4 + 2];
  float t3 = trans[i*16 + q*4 + 3];
  __shared__ float alpha[16];
  if (lane < 16) alpha[lane] = (lane == 14) ? 0.f : NEGV;
  __syncthreads();
  for (int t=0; t<TB; t++){
    if (x[b*TB + t] > 0){
      float a0 = alpha[q*4+0], a1 = alpha[q*4+1], a2 = alpha[q*4+2], a3 = alpha[q*4+3];
      float ht = emis[((long long)b*TB + t)*NTAG + i];
      float v0 = a0 + t0, v1 = a1 + t1, v2 = a2 + t2, v3 = a3 + t3;
      float mx = fmaxf(fmaxf(v0,v1), fmaxf(v2,v3));
      mx = fmaxf(mx, __shfl_xor(mx, 16));
      mx = fmaxf(mx, __shfl_xor(mx, 32));
      float sm = __expf(v0-mx) + __expf(v1-mx) + __expf(v2-mx) + __expf(v3-mx);
      sm += __shfl_xor(sm, 16);
      sm += __shfl_xor(sm, 32);
      float lse = mx + __logf(sm) + ht;
      __syncthreads();
      if (lane < 16) alpha[lane] = lse;
      __syncthreads();
    }
  }
  float av = -3.0e38f;
  if (lane < 16) av = alpha[lane] + trans[15*16 + lane];
  float mx = av;
  mx = fmaxf(mx, __shfl_xor(mx, 1));
  mx = fmaxf(mx, __shfl_xor(mx, 2));
  mx = fmaxf(mx, __shfl_xor(mx, 4));
  mx = fmaxf(mx, __shfl_xor(mx, 8));
  float sm = __expf(av - mx);
  sm += __shfl_xor(sm, 1);
  sm += __shfl_xor(sm, 2);
  sm += __shfl_xor(sm, 4);
  sm += __shfl_xor(sm, 8);
  if (lane == 0) out[b] = mx + __logf(sm);
}

// ---- CRF gold score: out[b] -= score ----
__global__ __launch_bounds__(64) void k_crf_score(const float* __restrict__ emis,
                                                  const float* __restrict__ trans,
                                                  const int* __restrict__ x,
                                                  const int* __restrict__ y,
                                                  float* __restrict__ out){
  int b = blockIdx.x;
  int lane = threadIdx.x;
  float part = 0.f; int cnt = 0;
  for (int t = lane; t < TB; t += 64){
    if (x[b*TB + t] > 0){
      int yt = y[b*TB + t];
      int prev = (t == 0) ? 14 : y[b*TB + t - 1];
      part += emis[((long long)b*TB + t)*NTAG + yt] + trans[yt*16 + prev];
      cnt++;
    }
  }
  #pragma unroll
  for (int d=1; d<64; d<<=1){ part += __shfl_xor(part, d); cnt += __shfl_xor(cnt, d); }
  if (lane == 0){
    int last = (cnt == 0) ? 14 : y[b*TB + cnt - 1];
    out[b] -= (part + trans[15*16 + last]);
  }
}

extern "C" void kernel_launch(void* const* d_in, const int* in_sizes, int n_in,
                              void* d_out, int out_size, void* d_ws, size_t ws_size,
                              hipStream_t stream){
  const int*   x     = (const int*)d_in[0];
  const int*   y     = (const int*)d_in[1];
  const float* emb   = (const float*)d_in[2];
  const float* Wih0  = (const float*)d_in[3];
  const float* Whh0  = (const float*)d_in[4];
  const float* bih0  = (const float*)d_in[5];
  const float* bhh0  = (const float*)d_in[6];
  const float* Wih1  = (const float*)d_in[7];
  const float* Whh1  = (const float*)d_in[8];
  const float* bih1  = (const float*)d_in[9];
  const float* bhh1  = (const float*)d_in[10];
  const float* Wout  = (const float*)d_in[11];
  const float* bout  = (const float*)d_in[12];
  const float* trans = (const float*)d_in[13];
  float* out = (float*)d_out;

  char* ws = (char*)d_ws;
  size_t off = 0;
  auto alloc = [&](size_t n){ char* p = ws + off; off = (off + n + 255) & ~(size_t)255; return p; };
  unsigned short* Abf  = (unsigned short*)alloc((size_t)MTOT*KP*2);
  unsigned short* Wbf0 = (unsigned short*)alloc((size_t)1216*KP*2);
  unsigned short* Wbf1 = (unsigned short*)alloc((size_t)1216*KP*2);
  float* bsum0 = (float*)alloc(1216*4);
  float* bsum1 = (float*)alloc(1216*4);
  float* pre   = (float*)alloc((size_t)2*MTOT*G4*4);
  float* h1    = (float*)alloc((size_t)MTOT*HID*4);
  float* h2    = (float*)alloc((size_t)MTOT*HID*4);
  float* emis  = (float*)alloc((size_t)MTOT*NTAG*4);

  hipLaunchKernelGGL(k_cvt_w, dim3(1520), dim3(256), 0, stream, Wih0, bih0, bhh0, Wbf0, bsum0);
  hipLaunchKernelGGL(k_cvt_w, dim3(1520), dim3(256), 0, stream, Wih1, bih1, bhh1, Wbf1, bsum1);
  hipLaunchKernelGGL(k_gather_embed, dim3(4096), dim3(256), 0, stream, x, emb, Abf);
  hipLaunchKernelGGL(k_proj, dim3(256,19), dim3(256), 0, stream, Abf, Wbf0, bsum0, pre);
  hipLaunchKernelGGL(k_rec, dim3(128), dim3(640), 0, stream, pre, Whh0, x, h1);
  hipLaunchKernelGGL(k_cvt_h, dim3(4096), dim3(256), 0, stream, h1, Abf);
  hipLaunchKernelGGL(k_proj, dim3(256,19), dim3(256), 0, stream, Abf, Wbf1, bsum1, pre);
  hipLaunchKernelGGL(k_rec, dim3(128), dim3(640), 0, stream, pre, Whh1, x, h2);
  hipLaunchKernelGGL(k_emis, dim3(2048), dim3(256), 0, stream, h2, Wout, bout, x, emis);
  hipLaunchKernelGGL(k_crf_part, dim3(64), dim3(64), 0, stream, emis, trans, x, out);
  hipLaunchKernelGGL(k_crf_score, dim3(64), dim3(64), 0, stream, emis, trans, x, y, out);
}